// Round 1
// baseline (593.202 us; speedup 1.0000x reference)
//
#include <hip/hip_runtime.h>
#include <hip/hip_fp16.h>

// RaBitQ forward: quantize (norm, rotate, sign, x0) + dequantize round trip.
// x: (4,16,4096,128) fp32 -> 262144 vectors of D=128.
// P: (128,128) fp32 orthonormal.
// out (all float32, concat flat): x_hat[262144*128] | packed[262144*16] |
//                                 norms16[262144]   | x016[262144]
//
// Geometry: block=256 (4 waves), grid=2048. Wave w owns vectors [w*32, w*32+32)
// as 4 tiles of 8. Lane l computes rotated coords e=l and e=l+64.
// P in LDS (64 KiB exactly), XOR-swizzled per row in 16B blocks: block j of
// row r stored at j ^ (r&7)  -> row reads (b128, lanes=rows) spread over all
// 32 banks; column reads (b32, lanes=cols) are a within-256B permutation.

#define NVEC_TOTAL (4 * 16 * 4096)

__device__ __forceinline__ float rfl_f(float v) {
  return __int_as_float(__builtin_amdgcn_readfirstlane(__float_as_int(v)));
}

__device__ __forceinline__ unsigned long long sel8_u64(const unsigned long long* a, int s) {
  // a[] is a fully-unrolled register array; all indices compile-time (rule #20).
  unsigned long long r0 = (s & 1) ? a[1] : a[0];
  unsigned long long r1 = (s & 1) ? a[3] : a[2];
  unsigned long long r2 = (s & 1) ? a[5] : a[4];
  unsigned long long r3 = (s & 1) ? a[7] : a[6];
  unsigned long long r4 = (s & 2) ? r1 : r0;
  unsigned long long r5 = (s & 2) ? r3 : r2;
  return (s & 4) ? r5 : r4;
}

__device__ __forceinline__ float sel8_f(const float* a, int s) {
  float r0 = (s & 1) ? a[1] : a[0];
  float r1 = (s & 1) ? a[3] : a[2];
  float r2 = (s & 1) ? a[5] : a[4];
  float r3 = (s & 1) ? a[7] : a[6];
  float r4 = (s & 2) ? r1 : r0;
  float r5 = (s & 2) ? r3 : r2;
  return (s & 4) ? r5 : r4;
}

__global__ __launch_bounds__(256, 2) void rabitq_fwd(const float* __restrict__ x,
                                                     const float* __restrict__ Pm,
                                                     float* __restrict__ out) {
  __shared__ __align__(16) float Pl[128 * 128];  // 64 KiB

  const int tid = threadIdx.x;
  const int lane = tid & 63;

  // ---- stage P into LDS, swizzled ----
  {
    const int r = tid >> 1;       // row 0..127, two threads per row
    const int half = tid & 1;
#pragma unroll
    for (int c = 0; c < 16; ++c) {
      const int dd = half * 64 + c * 4;                  // float col
      const int sj = (((dd >> 2) ^ (r & 7)) << 2);       // swizzled float col
      const float4 v = *(const float4*)(Pm + r * 128 + dd);
      *(float4*)(&Pl[r * 128 + sj]) = v;
    }
  }
  __syncthreads();

  const int w = blockIdx.x * 4 + (tid >> 6);  // global wave id, 0..8191
  float* const out_xhat = out;
  float* const out_pack = out + (size_t)NVEC_TOTAL * 128;
  float* const out_norm = out_pack + (size_t)NVEC_TOTAL * 16;
  float* const out_x0   = out_norm + NVEC_TOTAL;

  const int sw1 = lane & 7;  // row-swizzle key (same for lane and lane+64)

  for (int t = 0; t < 4; ++t) {
    const int vbase = w * 32 + t * 8;
    const float* const xb = x + (size_t)vbase * 128;

    // ================= quantize: x_rot_raw = x @ P^T =================
    float acc_lo[8], acc_hi[8];
#pragma unroll
    for (int v = 0; v < 8; ++v) { acc_lo[v] = 0.f; acc_hi[v] = 0.f; }

#pragma unroll 2
    for (int j = 0; j < 32; ++j) {
      const int js = ((j ^ sw1) << 2);
      const float4 pl = *(const float4*)(&Pl[lane * 128 + js]);
      const float4 ph = *(const float4*)(&Pl[(lane + 64) * 128 + js]);
#pragma unroll
      for (int v = 0; v < 8; ++v) {
        // wave-uniform address -> one coalesced/broadcast transaction, L1-hot
        const float4 xv = *(const float4*)(xb + v * 128 + j * 4);
        float al = acc_lo[v], ah = acc_hi[v];
        al = fmaf(xv.x, pl.x, al); ah = fmaf(xv.x, ph.x, ah);
        al = fmaf(xv.y, pl.y, al); ah = fmaf(xv.y, ph.y, ah);
        al = fmaf(xv.z, pl.z, al); ah = fmaf(xv.z, ph.z, ah);
        al = fmaf(xv.w, pl.w, al); ah = fmaf(xv.w, ph.w, ah);
        acc_lo[v] = al; acc_hi[v] = ah;
      }
    }

    // ---- signs, norm (rotation-invariant), x0 ----
    unsigned long long bl[8], bh[8];
    float n16v[8], x0v[8];
#pragma unroll
    for (int v = 0; v < 8; ++v) {
      bl[v] = __ballot(acc_lo[v] >= 0.0f);   // bit e = lane e, e=0..63
      bh[v] = __ballot(acc_hi[v] >= 0.0f);   // e=64..127
      const float a1 = fabsf(acc_lo[v]);
      const float a2 = fabsf(acc_hi[v]);
      float s1 = a1 + a2;                    // partial sum |x_rot|
      float n2 = fmaf(a1, a1, a2 * a2);      // partial sum x_rot^2
#pragma unroll
      for (int off = 32; off > 0; off >>= 1) {
        s1 += __shfl_xor(s1, off);
        n2 += __shfl_xor(n2, off);
      }
      float norm = fmaxf(sqrtf(n2), 1e-8f);  // == ||x|| (P orthonormal)
      const float n16  = __half2float(__float2half(norm));
      const float x0   = s1 / (128.0f * norm);
      const float x016 = __half2float(__float2half(x0));
      n16v[v] = rfl_f(n16);   // force SGPR (uniform by construction)
      x0v[v]  = rfl_f(x016);
    }

    // ---- store packed bytes (as floats), norms16, x016 ----
    {
      const int s = lane & 7;     // which of the 8 vectors
      const int jb = lane >> 3;   // which byte 0..7
      const unsigned long long el = sel8_u64(bl, s);
      const unsigned long long eh = sel8_u64(bh, s);
      const float fl = (float)((unsigned)(el >> (8 * jb)) & 255u);
      const float fh = (float)((unsigned)(eh >> (8 * jb)) & 255u);
      out_pack[(size_t)(vbase + s) * 16 + jb] = fl;       // bytes 0..7
      out_pack[(size_t)(vbase + s) * 16 + 8 + jb] = fh;   // bytes 8..15
      if (lane < 16) {
        const float nsel = sel8_f(n16v, s);
        const float xsel = sel8_f(x0v, s);
        if (lane < 8) out_norm[vbase + s] = nsel;
        else          out_x0[vbase + s] = xsel;
      }
    }

    // ================= dequantize: x_hat = n16 * (±x016) @ P ==========
    float dlo[8], dhi[8];
#pragma unroll
    for (int v = 0; v < 8; ++v) { dlo[v] = 0.f; dhi[v] = 0.f; }
    const int c1 = lane >> 2;        // 16B-block of column f=lane
    const int c2 = c1 + 16;          // column f=lane+64
    const int cb = lane & 3;

#pragma unroll 4
    for (int d = 0; d < 64; ++d) {
      const int rb = d * 128;
      const int k = d & 7;
      const float pl = Pl[rb + (((c1 ^ k) << 2) | cb)];
      const float ph = Pl[rb + (((c2 ^ k) << 2) | cb)];
#pragma unroll
      for (int v = 0; v < 8; ++v) {
        // uniform bits + uniform x016 -> SALU select, FMA gets SGPR operand
        const float sv = ((bl[v] >> d) & 1ULL) ? x0v[v] : -x0v[v];
        dlo[v] = fmaf(sv, pl, dlo[v]);
        dhi[v] = fmaf(sv, ph, dhi[v]);
      }
    }
#pragma unroll 4
    for (int d = 64; d < 128; ++d) {
      const int rb = d * 128;
      const int k = d & 7;
      const float pl = Pl[rb + (((c1 ^ k) << 2) | cb)];
      const float ph = Pl[rb + (((c2 ^ k) << 2) | cb)];
#pragma unroll
      for (int v = 0; v < 8; ++v) {
        const float sv = ((bh[v] >> (d - 64)) & 1ULL) ? x0v[v] : -x0v[v];
        dlo[v] = fmaf(sv, pl, dlo[v]);
        dhi[v] = fmaf(sv, ph, dhi[v]);
      }
    }

#pragma unroll
    for (int v = 0; v < 8; ++v) {
      const float sc = n16v[v];
      out_xhat[(size_t)(vbase + v) * 128 + lane]      = sc * dlo[v];
      out_xhat[(size_t)(vbase + v) * 128 + lane + 64] = sc * dhi[v];
    }
  }
}

extern "C" void kernel_launch(void* const* d_in, const int* in_sizes, int n_in,
                              void* d_out, int out_size, void* d_ws, size_t ws_size,
                              hipStream_t stream) {
  const float* x  = (const float*)d_in[0];
  const float* Pm = (const float*)d_in[1];
  float* out = (float*)d_out;
  // 262144 vectors / (4 waves * 4 tiles * 8 vec) = 2048 blocks, exact cover.
  hipLaunchKernelGGL(rabitq_fwd, dim3(2048), dim3(256), 0, stream, x, Pm, out);
}